// Round 9
// baseline (155.047 us; speedup 1.0000x reference)
//
#include <hip/hip_runtime.h>

#define NA 16
#define DD 513
#define ALPHA 0.1f
#define EPSV 1e-7f
#define GRID 2048   // 2048 blocks * 4 waves * 16 rows = 131072

typedef __fp16 h2v __attribute__((ext_vector_type(2)));
typedef float f32x2 __attribute__((ext_vector_type(2)));
typedef float f32x4 __attribute__((ext_vector_type(4)));
typedef unsigned int u32;
typedef unsigned long long u64;

union H2U { h2v h; u32 u; };
union FU  { float f; u32 u; int i; };

static __device__ __forceinline__ u32 pkrtz(float lo, float hi) {
    H2U t; t.h = __builtin_amdgcn_cvt_pkrtz(lo, hi); return t.u;
}
static __device__ __forceinline__ h2v asH2(u32 w) { H2U t; t.u = w; return t.h; }

// Row frame = 128 u32 (512 fp8). u32 a, byte c of row r  <->  element
// d = 1 + (a>>1) ... position p = 4a + c <-> d = 1 + (a>>1 of pair) ...
// concretely: pair-addr a = 2*l + h holds bytes c <-> d = 1 + l + 256h + 64c.
// XOR-swizzle on bits 1..4 keeps b64 pairs intact and all patterns bank-clean.
static __device__ __forceinline__ int swz(int row, int a) {
    return row * 128 + (a ^ ((row & 15) << 1));
}

__global__ __launch_bounds__(256, 4)
void hfield_kernel(const float* __restrict__ x,
                   const float* __restrict__ anc,
                   float* __restrict__ out) {
    __shared__ u32 bframe[NA * 128];        // anchors x16, fp8  (8 KB)
    __shared__ u32 xframe[4][16 * 128];     // x tiles, fp8      (8 KB/wave)

    const int tid = threadIdx.x, lane = tid & 63, wid = tid >> 6;
    const int col = lane & 15, g = lane >> 4;

    // ---- stage anchors (scaled x16 into fp8-normal range) ----
#pragma unroll
    for (int m = 0; m < 8; ++m) {
        const int i = m * 256 + tid;                 // 0..2047
        const int ar = i >> 7, a = i & 127, l = a >> 1, h = a & 1;
        const float* p = anc + ar * DD + 1 + l + 256 * h;
        int w = __builtin_amdgcn_cvt_pk_fp8_f32(p[0] * 16.f, p[64] * 16.f, 0, false);
        w = __builtin_amdgcn_cvt_pk_fp8_f32(p[128] * 16.f, p[192] * 16.f, w, true);
        bframe[swz(ar, a)] = (u32)w;
    }

    // ---- af0 for anchor `col` (f32 exact) ----
    float af0c;
    {
        const float* p = anc + col * DD + 1 + g * 128;
        float s = 0.f;
#pragma unroll 16
        for (int i = 0; i < 128; ++i) s = fmaf(p[i], p[i], s);
        s += __shfl_xor(s, 16);
        s += __shfl_xor(s, 32);
        af0c = sqrtf(1.0f + s);
    }
    __syncthreads();

    const int rowbase = (blockIdx.x * 4 + wid) * 16;
    u32* xf = xframe[wid];
    const float* xb = x + (size_t)rowbase * DD;

    // x0 for the 4 rows this lane-group owns (C row = 4g + r4)
    float x0r[4];
#pragma unroll
    for (int r4 = 0; r4 < 4; ++r4) x0r[r4] = xb[(size_t)(4 * g + r4) * DD];

    // ---- stage x tile: read once; fp8 copy -> LDS, f16 copy -> VGPRs ----
    u32 xq[16][4];                           // f16 pairs (v[2m], v[2m+1])
#pragma unroll
    for (int r = 0; r < 16; ++r) {
        const float* p = xb + (size_t)r * DD + 1 + lane;
        float v[8];
#pragma unroll
        for (int j = 0; j < 8; ++j) v[j] = p[64 * j];
#pragma unroll
        for (int m = 0; m < 4; ++m) xq[r][m] = pkrtz(v[2 * m], v[2 * m + 1]);
        int qa = __builtin_amdgcn_cvt_pk_fp8_f32(v[0], v[1], 0, false);
        qa = __builtin_amdgcn_cvt_pk_fp8_f32(v[2], v[3], qa, true);
        int qb = __builtin_amdgcn_cvt_pk_fp8_f32(v[4], v[5], 0, false);
        qb = __builtin_amdgcn_cvt_pk_fp8_f32(v[6], v[7], qb, true);
        *reinterpret_cast<uint2*>(&xf[swz(r, 2 * lane)]) = make_uint2((u32)qa, (u32)qb);
    }
    asm volatile("s_waitcnt lgkmcnt(0)" ::: "memory");

    // ---- MFMA: S[row][anchor] x16 rows x16 anchors, K=512 (fp8) ----
    f32x4 acc = {0.f, 0.f, 0.f, 0.f};
#pragma unroll
    for (int kt = 0; kt < 16; ++kt) {
        const int fi = swz(col, 8 * kt + 2 * g);
        const u64 A = *reinterpret_cast<const u64*>(&xf[fi]);
        const u64 B = *reinterpret_cast<const u64*>(&bframe[fi]);
        acc = __builtin_amdgcn_mfma_f32_16x16x32_fp8_fp8((long)A, (long)B, acc, 0, 0, 0);
    }

    // ---- theta, argmin, epilogue: 4 independent chains per lane ----
    const float thmin = 1.0f + 1e-7f;
    float c1r[4], c2r[4], o0r[4];
    int bir[4];
#pragma unroll
    for (int r4 = 0; r4 < 4; ++r4) {
        const float th = fmaxf(fmaf(x0r[r4], af0c, -acc[r4] * 0.0625f), thmin);
        FU u; u.f = th;
        u32 key = (u.u & 0xFFFFFFF0u) | (u32)col;
#pragma unroll
        for (int m = 1; m <= 8; m <<= 1) {
            const u32 o = (u32)__shfl_xor((int)key, m);
            key = o < key ? o : key;
        }
        const int bi  = (int)(key & 15u);
        const int src = (lane & 48) | bi;
        const float thw = __shfl(th, src);     // exact winner theta
        const float y0  = __shfl(af0c, src);   // winner af0

        const float s2 = thw * thw - 1.0f;
        const float rr = sqrtf(s2);
        const float ac = __logf(thw + rr);     // arccosh
        const float cf = ac / rr;
        const float vn = sqrtf(fmaxf(ALPHA * ALPHA * ac * ac, EPSV));
        const float e  = __expf(vn);
        const float ei = 1.0f / e;
        const float ch = 0.5f * (e + ei);
        const float sh = 0.5f * (e - ei);
        const float c2 = ALPHA * cf * (sh / vn);
        const float c1 = fmaf(-c2, thw, ch);

        c1r[r4] = c1;
        c2r[r4] = c2;
        o0r[r4] = fmaf(c2, y0, c1 * x0r[r4]);
        bir[r4] = bi;
    }

    // ---- store: 16 rows, sequential contiguous nt streams; x from regs ----
#pragma unroll
    for (int r = 0; r < 16; ++r) {
        const int src = (r >> 2) * 16;                   // producer group
        const float c1  = __shfl(c1r[r & 3], src);
        const float c2  = __shfl(c2r[r & 3], src);
        const float o0  = __shfl(o0r[r & 3], src);
        const int   bi  = __builtin_amdgcn_readfirstlane(__shfl(bir[r & 3], src));
        const float c2s = c2 * 0.0625f;                  // undo anchor x16

        const uint2 yq = *reinterpret_cast<const uint2*>(&bframe[swz(bi, 2 * lane)]);
        float yv[8];
        { f32x2 t = __builtin_amdgcn_cvt_pk_f32_fp8((int)yq.x, false); yv[0] = t.x; yv[1] = t.y; }
        { f32x2 t = __builtin_amdgcn_cvt_pk_f32_fp8((int)yq.x, true);  yv[2] = t.x; yv[3] = t.y; }
        { f32x2 t = __builtin_amdgcn_cvt_pk_f32_fp8((int)yq.y, false); yv[4] = t.x; yv[5] = t.y; }
        { f32x2 t = __builtin_amdgcn_cvt_pk_f32_fp8((int)yq.y, true);  yv[6] = t.x; yv[7] = t.y; }
        // byte c of u32 h  <->  d = 1 + lane + 256h + 64c  ->  j = 4h + c
        float ysl[8];
        ysl[0] = yv[0]; ysl[1] = yv[1]; ysl[2] = yv[2]; ysl[3] = yv[3];
        ysl[4] = yv[4]; ysl[5] = yv[5]; ysl[6] = yv[6]; ysl[7] = yv[7];
        // wait: yv already ordered by (h,c) pairs -> j = 4h + c:
        // yq.x false -> (c0,c1) -> j0,j1?  No: j = 4h + c with h=0: j = c.
        // cvt(false) gives bytes 0,1 -> j=0,1 ; cvt(true) bytes 2,3 -> j=2,3.
        // yq.y (h=1): j = 4+c. Ordering above is already correct.

        float* op = out + (size_t)(rowbase + r) * DD;
        if (lane == 0) __builtin_nontemporal_store(o0, op);
#pragma unroll
        for (int m = 0; m < 4; ++m) {
            const h2v hx = asH2(xq[r][m]);
            __builtin_nontemporal_store(fmaf(c2s, ysl[2 * m],     c1 * (float)hx.x),
                                        &op[1 + lane + 64 * (2 * m)]);
            __builtin_nontemporal_store(fmaf(c2s, ysl[2 * m + 1], c1 * (float)hx.y),
                                        &op[1 + lane + 64 * (2 * m + 1)]);
        }
    }
}

extern "C" void kernel_launch(void* const* d_in, const int* in_sizes, int n_in,
                              void* d_out, int out_size, void* d_ws, size_t ws_size,
                              hipStream_t stream) {
    const float* x   = (const float*)d_in[0];
    const float* anc = (const float*)d_in[1];
    float* out       = (float*)d_out;
    hipLaunchKernelGGL(hfield_kernel, dim3(GRID), dim3(256), 0, stream, x, anc, out);
}